// Round 1
// baseline (909.434 us; speedup 1.0000x reference)
//
#include <hip/hip_runtime.h>

// AdaptiveGraphConvolution on MI355X — round 1: correct fp32 baseline.
// N=64, C=64, T=300, V=25, S=3 subsets, IC=16, O=64.
//
// Phase 1 (k1): M[i,n,v1,v2] = sum_{ic,t} a_x[ic,t,v1]*b_x[ic,t,v2] / 4800
//   where a_x = a_w[i]@x + a_b, b_x likewise. Block per (n, 30-t chunk),
//   register accumulators, one atomicAdd pass at the end.
// Phase 2 (k2): softmax over v1 per (i,n,v2) + (A+graph_attn); also packs
//   g_w into bf16 [i][c][o] layout for k3.
// Phase 3 (k3): out[n,o,t,v2] = relu(BN(sum_i sum_v1 y_i[o,t,v1]*attn_i[n,v1,v2]
//   + sum_i g_b[i][o]) + x[n,o,t,v2]),  y_i = g_w[i]@x  (linearity swap: g_conv
//   applied before the attn matmul so z is never materialized in HBM).

#define NB 64
#define CB 64
#define TB 300
#define VB 25

typedef unsigned int uint32;
typedef unsigned short ushort16;

__device__ __forceinline__ ushort16 f2bf(float f) {
    uint32 u = __float_as_uint(f);
    u = u + 0x7FFFu + ((u >> 16) & 1u);
    return (ushort16)(u >> 16);
}
__device__ __forceinline__ float bf2f(ushort16 h) {
    return __uint_as_float(((uint32)h) << 16);
}

// ---------------------------------------------------------------- kernel 1
// grid 640 = 64 n * 10 chunks (30 t each, processed as 15 t-pairs), 256 thr
__global__ __launch_bounds__(256) void k1_attn_logits(
    const float* __restrict__ x, const float* __restrict__ a_w,
    const float* __restrict__ a_b, const float* __restrict__ b_w,
    const float* __restrict__ b_b, float* __restrict__ Mb)
{
    __shared__ __align__(16) char smem[61824];
    float* wsab = (float*)smem;            // [c=64][r=96 pad 100] transposed
    float* bias = (float*)(smem + 25600);  // [96]
    float* xs   = (float*)(smem + 25984);  // [2][64][28] (pads zeroed once)
    float* ab   = (float*)(smem + 40320);  // [2][96][28]

    const int tid = threadIdx.x;
    const int n   = blockIdx.x / 10;
    const int t0  = (blockIdx.x % 10) * 30;
    const float* xn = x + n * (CB * TB * VB);

    for (int idx = tid; idx < 96 * 64; idx += 256) {
        int r = idx >> 6, c = idx & 63;
        float v = (r < 48) ? a_w[r * 64 + c] : b_w[(r - 48) * 64 + c];
        wsab[c * 100 + r] = v;
    }
    for (int idx = tid; idx < 96; idx += 256)
        bias[idx] = (idx < 48) ? a_b[idx] : b_b[idx - 48];
    for (int idx = tid; idx < 2 * 64 * 3; idx += 256) {
        int tp = idx / 192, rem = idx % 192;
        int c = rem / 3, j = rem % 3;
        xs[(tp * 64 + c) * 28 + 25 + j] = 0.f;
    }

    float accA[2][4] = {}, accB[2][4] = {};

    for (int tp = 0; tp < 15; ++tp) {
        const int t = t0 + tp * 2;
        __syncthreads();  // protects xs (read in ab) and ab (read in M-accum)
        for (int idx = tid; idx < 2 * 64 * 25; idx += 256) {
            int tpar = idx / 1600, rem = idx % 1600;
            int c = rem / 25, v = rem % 25;
            xs[(tpar * 64 + c) * 28 + v] = xn[c * 7500 + (t + tpar) * 25 + v];
        }
        __syncthreads();
        // ab[tpar][r][v] = (w_r . x[:,t+tpar,v]) + bias_r ; 2-row x 4-col tiles
        for (int it = tid; it < 672; it += 256) {
            int tpar = it / 336, rem = it % 336;
            int rp = rem / 7, vg = rem % 7;
            int r0 = rp * 2;
            float a0x = 0, a0y = 0, a0z = 0, a0w = 0;
            float a1x = 0, a1y = 0, a1z = 0, a1w = 0;
            const float* xb = xs + tpar * 64 * 28 + vg * 4;
            #pragma unroll 8
            for (int c = 0; c < 64; ++c) {
                float2 w2 = *(const float2*)(wsab + c * 100 + r0);
                float4 xv = *(const float4*)(xb + c * 28);
                a0x += w2.x * xv.x; a0y += w2.x * xv.y;
                a0z += w2.x * xv.z; a0w += w2.x * xv.w;
                a1x += w2.y * xv.x; a1y += w2.y * xv.y;
                a1z += w2.y * xv.z; a1w += w2.y * xv.w;
            }
            float b0 = bias[r0], b1 = bias[r0 + 1];
            float4 s0 = { a0x + b0, a0y + b0, a0z + b0, a0w + b0 };
            float4 s1 = { a1x + b1, a1y + b1, a1z + b1, a1w + b1 };
            *(float4*)(ab + (tpar * 96 + r0) * 28 + vg * 4)     = s0;
            *(float4*)(ab + (tpar * 96 + r0 + 1) * 28 + vg * 4) = s1;
        }
        __syncthreads();
        // M partial accumulation into registers: items (i, v1-pair, v2-quad)
        {
            int k = 0;
            for (int it = tid; it < 273; it += 256, ++k) {
                int i = it / 91, rem = it % 91;
                int v1p = rem / 7, v2g = rem % 7;
                #pragma unroll
                for (int tpar = 0; tpar < 2; ++tpar) {
                    const float* abase = ab + (tpar * 96 + i * 16) * 28 + v1p * 2;
                    const float* bbase = ab + (tpar * 96 + 48 + i * 16) * 28 + v2g * 4;
                    #pragma unroll 4
                    for (int ic = 0; ic < 16; ++ic) {
                        float2 a2 = *(const float2*)(abase + ic * 28);
                        float4 b4 = *(const float4*)(bbase + ic * 28);
                        accA[k][0] += a2.x * b4.x; accA[k][1] += a2.x * b4.y;
                        accA[k][2] += a2.x * b4.z; accA[k][3] += a2.x * b4.w;
                        accB[k][0] += a2.y * b4.x; accB[k][1] += a2.y * b4.y;
                        accB[k][2] += a2.y * b4.z; accB[k][3] += a2.y * b4.w;
                    }
                }
            }
        }
    }

    const float inv = 1.0f / 4800.0f;
    {
        int k = 0;
        for (int it = tid; it < 273; it += 256, ++k) {
            int i = it / 91, rem = it % 91;
            int v1p = rem / 7, v2g = rem % 7;
            int v1a = v1p * 2, v1b = v1a + 1;
            #pragma unroll
            for (int j = 0; j < 4; ++j) {
                int v2 = v2g * 4 + j;
                if (v2 < 25) {
                    atomicAdd(Mb + ((i * NB + n) * 25 + v1a) * 25 + v2, accA[k][j] * inv);
                    if (v1b < 25)
                        atomicAdd(Mb + ((i * NB + n) * 25 + v1b) * 25 + v2, accB[k][j] * inv);
                }
            }
        }
    }
}

// ---------------------------------------------------------------- kernel 2
// softmax over v1 (axis=-2) per (i,n,v2) + A_tot;  plus g_w -> bf16 pack
__global__ __launch_bounds__(256) void k2_softmax_prep(
    const float* __restrict__ Mb, const float* __restrict__ A,
    const float* __restrict__ GA, const float* __restrict__ g_w,
    float* __restrict__ attn, uint32* __restrict__ gwt)
{
    int idx = blockIdx.x * 256 + threadIdx.x;
    if (idx < 4800) {
        int v2 = idx % 25, n = (idx / 25) % 64, i = idx / 1600;
        const float* mcol = Mb + ((i * 64 + n) * 25) * 25 + v2;
        float e[25], mx = -1e30f;
        #pragma unroll
        for (int v1 = 0; v1 < 25; ++v1) { e[v1] = mcol[v1 * 25]; mx = fmaxf(mx, e[v1]); }
        float s = 0.f;
        #pragma unroll
        for (int v1 = 0; v1 < 25; ++v1) { e[v1] = __expf(e[v1] - mx); s += e[v1]; }
        float invs = 1.0f / s;
        float* ocol = attn + ((i * 64 + n) * 25) * 25 + v2;
        const float* acol = A + i * 625 + v2;
        const float* gcol = GA + i * 625 + v2;
        #pragma unroll
        for (int v1 = 0; v1 < 25; ++v1)
            ocol[v1 * 25] = e[v1] * invs + acol[v1 * 25] + gcol[v1 * 25];
    } else if (idx < 4800 + 6144) {
        int id2 = idx - 4800;
        int i = id2 / 2048, rem = id2 % 2048;
        int c = rem / 32, oo = rem % 32;
        ushort16 lo = f2bf(g_w[(i * 64 + 2 * oo) * 64 + c]);
        ushort16 hi = f2bf(g_w[(i * 64 + 2 * oo + 1) * 64 + c]);
        gwt[(i * 64 + c) * 32 + oo] = ((uint32)hi << 16) | (uint32)lo;
    }
}

// ---------------------------------------------------------------- kernel 3
// grid 4800 = 64 n * 75 t-chunks(4), 256 thr = 64 o x 4 ts
__global__ __launch_bounds__(256) void k3_out(
    const float* __restrict__ x, const float* __restrict__ attn,
    const uint32* __restrict__ gwt, const float* __restrict__ g_b,
    const float* __restrict__ bn_g, const float* __restrict__ bn_b,
    const float* __restrict__ bn_m, const float* __restrict__ bn_v,
    float* __restrict__ out)
{
    __shared__ __align__(16) char smem[61648];
    ushort16* gws = (ushort16*)smem;       // [3][64 c][64 o] bf16
    float* ats = (float*)(smem + 24576);   // [3][25][28]
    float* xs  = (float*)(smem + 32976);   // [4][64][28]
    float* outs = (float*)(smem + 32976);  // alias: [64][101] after compute

    const int tid = threadIdx.x;
    const int n  = blockIdx.x / 75;
    const int t0 = (blockIdx.x % 75) * 4;
    const float* xn = x + n * (CB * TB * VB);

    for (int idx = tid; idx < 6144; idx += 256)
        ((uint32*)gws)[idx] = gwt[idx];
    for (int idx = tid; idx < 1875; idx += 256) {
        int i = idx / 625, rem = idx % 625;
        int v1 = rem / 25, v2 = rem % 25;
        ats[(i * 25 + v1) * 28 + v2] = attn[((i * 64 + n) * 25 + v1) * 25 + v2];
    }
    for (int idx = tid; idx < 225; idx += 256) {
        int i = idx / 75, rem = idx % 75;
        int v1 = rem / 3, j = rem % 3;
        ats[(i * 25 + v1) * 28 + 25 + j] = 0.f;
    }
    for (int idx = tid; idx < 4 * 64 * 25; idx += 256) {
        int ts = idx / 1600, rem = idx % 1600;
        int c = rem / 25, v = rem % 25;
        xs[(ts * 64 + c) * 28 + v] = xn[c * 7500 + (t0 + ts) * 25 + v];
    }
    for (int idx = tid; idx < 4 * 64 * 3; idx += 256) {
        int ts = idx / 192, rem = idx % 192;
        int c = rem / 3, j = rem % 3;
        xs[(ts * 64 + c) * 28 + 25 + j] = 0.f;
    }
    __syncthreads();

    const int o  = tid & 63;   // wave-uniform ts -> x reads broadcast
    const int ts = tid >> 6;
    const float* xb = xs + ts * 64 * 28;

    float acc[28];
    #pragma unroll
    for (int q = 0; q < 28; ++q) acc[q] = 0.f;

    #pragma unroll
    for (int i = 0; i < 3; ++i) {
        float y[28];
        #pragma unroll
        for (int q = 0; q < 28; ++q) y[q] = 0.f;
        const ushort16* gw = gws + (i * 64) * 64 + o;
        #pragma unroll 4
        for (int c = 0; c < 64; ++c) {
            float w = bf2f(gw[c * 64]);
            const float4* xr = (const float4*)(xb + c * 28);
            #pragma unroll
            for (int g = 0; g < 7; ++g) {
                float4 xv = xr[g];
                y[g * 4 + 0] += w * xv.x; y[g * 4 + 1] += w * xv.y;
                y[g * 4 + 2] += w * xv.z; y[g * 4 + 3] += w * xv.w;
            }
        }
        const float* at = ats + i * 25 * 28;
        #pragma unroll 5
        for (int v1 = 0; v1 < 25; ++v1) {
            float yv = y[v1];
            const float4* ar = (const float4*)(at + v1 * 28);
            #pragma unroll
            for (int g = 0; g < 7; ++g) {
                float4 av = ar[g];
                acc[g * 4 + 0] += yv * av.x; acc[g * 4 + 1] += yv * av.y;
                acc[g * 4 + 2] += yv * av.z; acc[g * 4 + 3] += yv * av.w;
            }
        }
    }

    const float gb = g_b[o] + g_b[64 + o] + g_b[128 + o];
    const float sc = bn_g[o] * rsqrtf(bn_v[o] + 1e-5f);
    const float mu = bn_m[o], bt = bn_b[o];
    #pragma unroll
    for (int v2 = 0; v2 < 25; ++v2) {
        float h = (acc[v2] + gb - mu) * sc + bt + xb[o * 28 + v2];
        acc[v2] = fmaxf(h, 0.f);
    }
    __syncthreads();  // all residual reads of xs done before aliasing
    #pragma unroll
    for (int v2 = 0; v2 < 25; ++v2)
        outs[o * 101 + ts * 25 + v2] = acc[v2];
    __syncthreads();
    float* og = out + n * (CB * TB * VB) + t0 * 25;
    for (int idx = tid; idx < 6400; idx += 256) {
        int oo = idx / 100, p = idx % 100;
        og[oo * 7500 + p] = outs[oo * 101 + p];
    }
}

// ---------------------------------------------------------------- launch
extern "C" void kernel_launch(void* const* d_in, const int* in_sizes, int n_in,
                              void* d_out, int out_size, void* d_ws, size_t ws_size,
                              hipStream_t stream) {
    const float* x    = (const float*)d_in[0];
    const float* A    = (const float*)d_in[1];
    const float* GA   = (const float*)d_in[2];
    const float* g_w  = (const float*)d_in[3];
    const float* g_b  = (const float*)d_in[4];
    const float* a_w  = (const float*)d_in[5];
    const float* a_b  = (const float*)d_in[6];
    const float* b_w  = (const float*)d_in[7];
    const float* b_b  = (const float*)d_in[8];
    const float* bn_g = (const float*)d_in[9];
    const float* bn_b = (const float*)d_in[10];
    const float* bn_m = (const float*)d_in[11];
    const float* bn_v = (const float*)d_in[12];
    float* out = (float*)d_out;

    // ws layout: M logits [3*64*625] f32 (480000 B) | attn [same] (480000 B)
    //            | gwt bf16-packed (24576 B)
    float*  Mb   = (float*)d_ws;
    float*  attn = Mb + 120000;
    uint32* gwt  = (uint32*)((char*)d_ws + 960000);

    hipMemsetAsync(d_ws, 0, 480000, stream);  // zero M accumulators
    k1_attn_logits<<<dim3(640), dim3(256), 0, stream>>>(x, a_w, a_b, b_w, b_b, Mb);
    k2_softmax_prep<<<dim3(43), dim3(256), 0, stream>>>(Mb, A, GA, g_w, attn, gwt);
    k3_out<<<dim3(4800), dim3(256), 0, stream>>>(x, attn, gwt, g_b, bn_g, bn_b,
                                                 bn_m, bn_v, out);
}

// Round 2
// 669.894 us; speedup vs baseline: 1.3576x; 1.3576x over previous
//
#include <hip/hip_runtime.h>

// AdaptiveGraphConvolution on MI355X — round 2: k3 rewritten with MFMA.
// N=64, C=64, T=300, V=25, S=3 subsets, IC=16, O=64.
//
// k1 (unchanged, passing): attn logits M via fp32 VALU + atomicAdd.
// k2: softmax over v1 + A_tot -> emits attn TRANSPOSED bf16 atT[i][n][v2][v1 pad32]
//     (B-operand layout for k3's xa-MFMA) and gw_bf[o][k=i*64+c] bf16
//     (A-operand layout for k3's main MFMA).
// k3: per block (n, 5 t):
//     xs[c][t][v1p32] bf16  (zero-padded v1>=25)
//     for i: xa-MFMA: xa[col=(t,v2)][c] = sum_v1 x[c,t,v1]*attn_i[v1,v2]
//            main-MFMA: acc[o][col] += gw_i[o][c]*xa[c][col]   (K=c, accum over i)
//     epilogue: BN(scale/shift prefolded) + residual(from xs) + relu, direct store.

#define NB 64
#define CB 64
#define TB 300
#define VB 25

typedef unsigned int uint32;
typedef unsigned short ushort16;
typedef __attribute__((ext_vector_type(8))) short short8;
typedef __attribute__((ext_vector_type(4))) float f32x4;

__device__ __forceinline__ ushort16 f2bf(float f) {
    uint32 u = __float_as_uint(f);
    u = u + 0x7FFFu + ((u >> 16) & 1u);
    return (ushort16)(u >> 16);
}
__device__ __forceinline__ float bf2f(ushort16 h) {
    return __uint_as_float(((uint32)h) << 16);
}
__device__ __forceinline__ uint32 packbf2(float a, float b) {
    return (uint32)f2bf(a) | ((uint32)f2bf(b) << 16);
}

// ---------------------------------------------------------------- kernel 1
// UNCHANGED from round 1 (passing). grid 640 = 64 n * 10 chunks, 256 thr
__global__ __launch_bounds__(256) void k1_attn_logits(
    const float* __restrict__ x, const float* __restrict__ a_w,
    const float* __restrict__ a_b, const float* __restrict__ b_w,
    const float* __restrict__ b_b, float* __restrict__ Mb)
{
    __shared__ __align__(16) char smem[61824];
    float* wsab = (float*)smem;            // [c=64][r=96 pad 100] transposed
    float* bias = (float*)(smem + 25600);  // [96]
    float* xs   = (float*)(smem + 25984);  // [2][64][28]
    float* ab   = (float*)(smem + 40320);  // [2][96][28]

    const int tid = threadIdx.x;
    const int n   = blockIdx.x / 10;
    const int t0  = (blockIdx.x % 10) * 30;
    const float* xn = x + n * (CB * TB * VB);

    for (int idx = tid; idx < 96 * 64; idx += 256) {
        int r = idx >> 6, c = idx & 63;
        float v = (r < 48) ? a_w[r * 64 + c] : b_w[(r - 48) * 64 + c];
        wsab[c * 100 + r] = v;
    }
    for (int idx = tid; idx < 96; idx += 256)
        bias[idx] = (idx < 48) ? a_b[idx] : b_b[idx - 48];
    for (int idx = tid; idx < 2 * 64 * 3; idx += 256) {
        int tp = idx / 192, rem = idx % 192;
        int c = rem / 3, j = rem % 3;
        xs[(tp * 64 + c) * 28 + 25 + j] = 0.f;
    }

    float accA[2][4] = {}, accB[2][4] = {};

    for (int tp = 0; tp < 15; ++tp) {
        const int t = t0 + tp * 2;
        __syncthreads();
        for (int idx = tid; idx < 2 * 64 * 25; idx += 256) {
            int tpar = idx / 1600, rem = idx % 1600;
            int c = rem / 25, v = rem % 25;
            xs[(tpar * 64 + c) * 28 + v] = xn[c * 7500 + (t + tpar) * 25 + v];
        }
        __syncthreads();
        for (int it = tid; it < 672; it += 256) {
            int tpar = it / 336, rem = it % 336;
            int rp = rem / 7, vg = rem % 7;
            int r0 = rp * 2;
            float a0x = 0, a0y = 0, a0z = 0, a0w = 0;
            float a1x = 0, a1y = 0, a1z = 0, a1w = 0;
            const float* xb = xs + tpar * 64 * 28 + vg * 4;
            #pragma unroll 8
            for (int c = 0; c < 64; ++c) {
                float2 w2 = *(const float2*)(wsab + c * 100 + r0);
                float4 xv = *(const float4*)(xb + c * 28);
                a0x += w2.x * xv.x; a0y += w2.x * xv.y;
                a0z += w2.x * xv.z; a0w += w2.x * xv.w;
                a1x += w2.y * xv.x; a1y += w2.y * xv.y;
                a1z += w2.y * xv.z; a1w += w2.y * xv.w;
            }
            float b0 = bias[r0], b1 = bias[r0 + 1];
            float4 s0 = { a0x + b0, a0y + b0, a0z + b0, a0w + b0 };
            float4 s1 = { a1x + b1, a1y + b1, a1z + b1, a1w + b1 };
            *(float4*)(ab + (tpar * 96 + r0) * 28 + vg * 4)     = s0;
            *(float4*)(ab + (tpar * 96 + r0 + 1) * 28 + vg * 4) = s1;
        }
        __syncthreads();
        {
            int k = 0;
            for (int it = tid; it < 273; it += 256, ++k) {
                int i = it / 91, rem = it % 91;
                int v1p = rem / 7, v2g = rem % 7;
                #pragma unroll
                for (int tpar = 0; tpar < 2; ++tpar) {
                    const float* abase = ab + (tpar * 96 + i * 16) * 28 + v1p * 2;
                    const float* bbase = ab + (tpar * 96 + 48 + i * 16) * 28 + v2g * 4;
                    #pragma unroll 4
                    for (int ic = 0; ic < 16; ++ic) {
                        float2 a2 = *(const float2*)(abase + ic * 28);
                        float4 b4 = *(const float4*)(bbase + ic * 28);
                        accA[k][0] += a2.x * b4.x; accA[k][1] += a2.x * b4.y;
                        accA[k][2] += a2.x * b4.z; accA[k][3] += a2.x * b4.w;
                        accB[k][0] += a2.y * b4.x; accB[k][1] += a2.y * b4.y;
                        accB[k][2] += a2.y * b4.z; accB[k][3] += a2.y * b4.w;
                    }
                }
            }
        }
    }

    const float inv = 1.0f / 4800.0f;
    {
        int k = 0;
        for (int it = tid; it < 273; it += 256, ++k) {
            int i = it / 91, rem = it % 91;
            int v1p = rem / 7, v2g = rem % 7;
            int v1a = v1p * 2, v1b = v1a + 1;
            #pragma unroll
            for (int j = 0; j < 4; ++j) {
                int v2 = v2g * 4 + j;
                if (v2 < 25) {
                    atomicAdd(Mb + ((i * NB + n) * 25 + v1a) * 25 + v2, accA[k][j] * inv);
                    if (v1b < 25)
                        atomicAdd(Mb + ((i * NB + n) * 25 + v1b) * 25 + v2, accB[k][j] * inv);
                }
            }
        }
    }
}

// ---------------------------------------------------------------- kernel 2
// softmax over v1 per (i,n,v2) + A_tot -> atT bf16 [i][n][v2][v1 pad32]
// plus g_w -> gw_bf bf16 [o][k=i*64+c] (A-operand layout for k3)
__global__ __launch_bounds__(256) void k2_softmax_prep(
    const float* __restrict__ Mb, const float* __restrict__ A,
    const float* __restrict__ GA, const float* __restrict__ g_w,
    uint32* __restrict__ atT, uint32* __restrict__ gwb)
{
    int idx = blockIdx.x * 256 + threadIdx.x;
    if (idx < 4800) {
        int v2 = idx % 25, n = (idx / 25) % 64, i = idx / 1600;
        const float* mcol = Mb + ((i * 64 + n) * 25) * 25 + v2;
        float e[25], mx = -1e30f;
        #pragma unroll
        for (int v1 = 0; v1 < 25; ++v1) { e[v1] = mcol[v1 * 25]; mx = fmaxf(mx, e[v1]); }
        float s = 0.f;
        #pragma unroll
        for (int v1 = 0; v1 < 25; ++v1) { e[v1] = __expf(e[v1] - mx); s += e[v1]; }
        float invs = 1.0f / s;
        const float* acol = A + i * 625 + v2;
        const float* gcol = GA + i * 625 + v2;
        float w[25];
        #pragma unroll
        for (int v1 = 0; v1 < 25; ++v1)
            w[v1] = e[v1] * invs + acol[v1 * 25] + gcol[v1 * 25];
        uint32* row = atT + ((i * 64 + n) * 32 + v2) * 16;
        #pragma unroll
        for (int p = 0; p < 12; ++p) row[p] = packbf2(w[2 * p], w[2 * p + 1]);
        row[12] = (uint32)f2bf(w[24]);
        row[13] = 0u; row[14] = 0u; row[15] = 0u;
    } else if (idx < 4800 + 6144) {
        int j = idx - 4800;
        int o = j / 96, kp = j % 96;
        int k0 = 2 * kp;
        int i = k0 >> 6, c = k0 & 63;
        float lo = g_w[(i * 64 + o) * 64 + c];
        float hi = g_w[(i * 64 + o) * 64 + c + 1];
        gwb[o * 96 + kp] = packbf2(lo, hi);
    }
}

// ---------------------------------------------------------------- kernel 3
// MFMA. grid 3840 = 64 n * 60 chunks of 5 t; 256 thr = 4 waves (wave=o/c tile)
__global__ __launch_bounds__(256) void k3_out(
    const float* __restrict__ x, const uint32* __restrict__ atT,
    const ushort16* __restrict__ gwb, const float* __restrict__ g_b,
    const float* __restrict__ bn_g, const float* __restrict__ bn_b,
    const float* __restrict__ bn_m, const float* __restrict__ bn_v,
    float* __restrict__ out)
{
    __shared__ ushort16 xs[64 * 168];   // [c][t*32 + v1]  (stride 168: 2-way banks)
    __shared__ uint32  xa[128 * 36];    // [col=(t,v2) pad128][c: 72 bf16 as 36 u32]
    __shared__ uint32  ats[3 * 32 * 20];// [i][v2][v1: 40 bf16 as 20 u32]
    __shared__ float   bsc[64], bsh[64];

    const int tid = threadIdx.x;
    const int n  = blockIdx.x / 60;
    const int t0 = (blockIdx.x % 60) * 5;

    // stage x tile -> bf16 [c][t][v1]
    for (int idx = tid; idx < 8000; idx += 256) {
        int c = idx / 125, tv = idx % 125;
        int t = tv / 25, v = tv % 25;
        float g = x[((n * 64 + c) * 300 + t0 + t) * 25 + v];
        xs[c * 168 + t * 32 + v] = f2bf(g);
    }
    for (int idx = tid; idx < 64 * 35; idx += 256) {   // zero v1 in [25,32)
        int c = idx / 35, r = idx % 35;
        xs[c * 168 + (r / 7) * 32 + 25 + (r % 7)] = (ushort16)0;
    }
    // stage attn^T rows for this n
    for (int idx = tid; idx < 1536; idx += 256) {
        int row = idx >> 4, d = idx & 15;   // row = i*32+v2
        ats[row * 20 + d] = atT[((row >> 5) * 64 + n) * 512 + (row & 31) * 16 + d];
    }
    // BN scale/shift prefold (h = acc*sc + sh + x)
    for (int idx = tid; idx < 64; idx += 256) {
        float sc = bn_g[idx] * rsqrtf(bn_v[idx] + 1e-5f);
        bsc[idx] = sc;
        bsh[idx] = (g_b[idx] + g_b[64 + idx] + g_b[128 + idx] - bn_m[idx]) * sc + bn_b[idx];
    }
    // zero xa pad rows (cols 125..127)
    for (int idx = tid; idx < 3 * 36; idx += 256)
        xa[(125 + idx / 36) * 36 + idx % 36] = 0u;

    const int w    = tid >> 6;      // wave id = o-tile (main) = c-tile (xa)
    const int lane = tid & 63;
    const int l15  = lane & 15;
    const int q    = lane >> 4;

    // preload A-frags of gw (all 6 K-steps: k = i*64 + s*32)
    short8 gf[6];
    #pragma unroll
    for (int s = 0; s < 6; ++s)
        gf[s] = *(const short8*)(gwb + ((w * 16 + l15) * 192 + s * 32 + q * 8));

    f32x4 acc[8];
    #pragma unroll
    for (int ct = 0; ct < 8; ++ct) acc[ct] = (f32x4){0.f, 0.f, 0.f, 0.f};
    const f32x4 zf = (f32x4){0.f, 0.f, 0.f, 0.f};

    __syncthreads();

    for (int i = 0; i < 3; ++i) {
        if (i) __syncthreads();   // previous xa fully consumed
        // ---- xa-phase: this wave produces c-rows [w*16, w*16+16)
        #pragma unroll
        for (int t = 0; t < 5; ++t) {
            short8 ax = *(const short8*)(xs + (w * 16 + l15) * 168 + t * 32 + q * 8);
            #pragma unroll
            for (int vt = 0; vt < 2; ++vt) {
                short8 bt = *(const short8*)((const ushort16*)ats +
                                             (i * 32 + vt * 16 + l15) * 40 + q * 8);
                f32x4 d = __builtin_amdgcn_mfma_f32_16x16x32_bf16(ax, bt, zf, 0, 0, 0);
                int v2 = vt * 16 + l15;
                if (v2 < 25) {
                    int col = t * 25 + v2;
                    int c0  = w * 16 + q * 4;
                    xa[col * 36 + (c0 >> 1)]     = packbf2(d[0], d[1]);
                    xa[col * 36 + (c0 >> 1) + 1] = packbf2(d[2], d[3]);
                }
            }
        }
        __syncthreads();
        // ---- main GEMM: acc[o,col] += gw_i[o,c] * xa[c,col]
        #pragma unroll
        for (int ct = 0; ct < 8; ++ct) {
            #pragma unroll
            for (int s = 0; s < 2; ++s) {
                short8 bfrag = *(const short8*)((const ushort16*)xa +
                                                (ct * 16 + l15) * 72 + s * 32 + q * 8);
                acc[ct] = __builtin_amdgcn_mfma_f32_16x16x32_bf16(
                    gf[i * 2 + s], bfrag, acc[ct], 0, 0, 0);
            }
        }
    }

    // ---- epilogue: BN + residual (bf16 xs) + relu, direct coalesced store
    const int o0 = w * 16 + q * 4;
    #pragma unroll
    for (int ct = 0; ct < 8; ++ct) {
        int col = ct * 16 + l15;
        if (col < 125) {
            int tl = col / 25;
            int v  = col - tl * 25;
            float* ob = out + (n * 64 + o0) * 7500 + t0 * 25 + col;
            #pragma unroll
            for (int r = 0; r < 4; ++r) {
                int o = o0 + r;
                float xv = bf2f(xs[o * 168 + tl * 32 + v]);
                float h = acc[ct][r] * bsc[o] + bsh[o] + xv;
                ob[r * 7500] = fmaxf(h, 0.f);
            }
        }
    }
}

// ---------------------------------------------------------------- launch
extern "C" void kernel_launch(void* const* d_in, const int* in_sizes, int n_in,
                              void* d_out, int out_size, void* d_ws, size_t ws_size,
                              hipStream_t stream) {
    const float* x    = (const float*)d_in[0];
    const float* A    = (const float*)d_in[1];
    const float* GA   = (const float*)d_in[2];
    const float* g_w  = (const float*)d_in[3];
    const float* g_b  = (const float*)d_in[4];
    const float* a_w  = (const float*)d_in[5];
    const float* a_b  = (const float*)d_in[6];
    const float* b_w  = (const float*)d_in[7];
    const float* b_b  = (const float*)d_in[8];
    const float* bn_g = (const float*)d_in[9];
    const float* bn_b = (const float*)d_in[10];
    const float* bn_m = (const float*)d_in[11];
    const float* bn_v = (const float*)d_in[12];
    float* out = (float*)d_out;

    // ws: Mb f32[120000] (480000 B) | atT bf16 [3][64][32][32] (393216 B)
    //     | gw_bf bf16 [64][192] (24576 B)
    float*  Mb  = (float*)d_ws;
    uint32* atT = (uint32*)((char*)d_ws + 480000);
    uint32* gwb = (uint32*)((char*)d_ws + 480000 + 393216);

    hipMemsetAsync(d_ws, 0, 480000, stream);  // zero M accumulators
    k1_attn_logits<<<dim3(640), dim3(256), 0, stream>>>(x, a_w, a_b, b_w, b_b, Mb);
    k2_softmax_prep<<<dim3(43), dim3(256), 0, stream>>>(Mb, A, GA, g_w, atT, gwb);
    k3_out<<<dim3(3840), dim3(256), 0, stream>>>(x, atT, (const ushort16*)gwb,
                                                 g_b, bn_g, bn_b, bn_m, bn_v, out);
}

// Round 3
// 371.068 us; speedup vs baseline: 2.4509x; 1.8053x over previous
//
#include <hip/hip_runtime.h>

// AdaptiveGraphConvolution on MI355X — round 3: k1 rewritten with MFMA.
// N=64, C=64, T=300, V=25, S=3 subsets, IC=16, O=64.
//
// k1 (NEW, MFMA): block per (n, 12-t chunk), 3 sub-chunks of 4 t.
//   Phase A: ab[96 r][100 tv] = W[96x64] @ x  (16x16x32 bf16 MFMA),
//            D-frags + bias written packed into operand layout
//            abT[group g][v][k=(t_local,ic)]  (g<3: a_i, g>=3: b_i).
//   Phase B: M_i[v1][v2] += a_i^T b_i  (32x32x16 bf16 MFMA, wave w owns t=w),
//            accumulated in AGPRs across sub-chunks; 4-wave LDS reduce;
//            atomicAdd *1/4800 into Mb.
//   LDS ops use XOR k-block swizzle (kb' = (kb + row) & 7): 16B-aligned
//   ds_read_b128 rows with no padding, ~2-way banks.
// k2 (unchanged): softmax over v1 + A_tot -> atT bf16; g_w -> gwb bf16.
// k3 (unchanged): linearity-swapped MFMA output kernel.

#define NB 64
#define CB 64
#define TB 300
#define VB 25

typedef unsigned int uint32;
typedef unsigned short ushort16;
typedef __attribute__((ext_vector_type(8))) short short8;
typedef __attribute__((ext_vector_type(4))) float f32x4;
typedef __attribute__((ext_vector_type(16))) float f32x16;

__device__ __forceinline__ ushort16 f2bf(float f) {
    uint32 u = __float_as_uint(f);
    u = u + 0x7FFFu + ((u >> 16) & 1u);
    return (ushort16)(u >> 16);
}
__device__ __forceinline__ float bf2f(ushort16 h) {
    return __uint_as_float(((uint32)h) << 16);
}
__device__ __forceinline__ uint32 packbf2(float a, float b) {
    return (uint32)f2bf(a) | ((uint32)f2bf(b) << 16);
}

// ---------------------------------------------------------------- kernel 1
// grid 1600 = 64 n * 25 chunks (12 t), 256 thr = 4 waves
__global__ __launch_bounds__(256) void k1_attn_logits_mfma(
    const float* __restrict__ x, const float* __restrict__ a_w,
    const float* __restrict__ a_b, const float* __restrict__ b_w,
    const float* __restrict__ b_b, float* __restrict__ Mb)
{
    __shared__ ushort16 ws[96 * 64];    // W bf16, row r, k-block swizzled
    __shared__ ushort16 xT[112 * 64];   // x^T bf16 [tv][c], swizzled; reused as Ms
    __shared__ ushort16 abT[192 * 64];  // [g*32+v][k=(tl,ic)] bf16, swizzled
    __shared__ float    bias[96];

    const int tid   = threadIdx.x;
    const int n     = blockIdx.x / 25;
    const int chunk = blockIdx.x % 25;
    const float* xn = x + n * (CB * TB * VB);

    // W -> bf16 swizzled LDS (rows 0..47 = a_w, 48..95 = b_w)
    for (int idx = tid; idx < 6144; idx += 256) {
        int r = idx >> 6, c = idx & 63;
        float v = (r < 48) ? a_w[r * 64 + c] : b_w[(r - 48) * 64 + c];
        ws[r * 64 + ((((c >> 3) + r) & 7) << 3) + (c & 7)] = f2bf(v);
    }
    for (int idx = tid; idx < 96; idx += 256)
        bias[idx] = (idx < 48) ? a_b[idx] : b_b[idx - 48];

    const int w    = tid >> 6;
    const int lane = tid & 63;
    const int l15  = lane & 15;
    const int q    = lane >> 4;
    const int hi   = lane >> 5;
    const int v32  = lane & 31;

    f32x16 acc[3];
    #pragma unroll
    for (int i = 0; i < 3; ++i)
        #pragma unroll
        for (int r = 0; r < 16; ++r) acc[i][r] = 0.f;
    const f32x4 zf = (f32x4){0.f, 0.f, 0.f, 0.f};

    for (int s = 0; s < 3; ++s) {
        __syncthreads();   // previous iter's xT/abT consumers done
        // ---- stage x^T sub-chunk (4 t = 100 contiguous floats per c-row)
        const float* xs0 = xn + (chunk * 12 + s * 4) * 25;
        for (int idx = tid; idx < 1600; idx += 256) {
            int c = idx / 25, j = idx % 25;
            float4 v4 = *(const float4*)(xs0 + c * 7500 + j * 4);
            int tv0 = j * 4;
            #pragma unroll
            for (int e = 0; e < 4; ++e) {
                int tv = tv0 + e;
                float fv = (e == 0) ? v4.x : (e == 1) ? v4.y : (e == 2) ? v4.z : v4.w;
                xT[tv * 64 + ((((c >> 3) + tv) & 7) << 3) + (c & 7)] = f2bf(fv);
            }
        }
        __syncthreads();
        // ---- phase A: ab = W @ x, write frags into abT operand layout
        for (int tile = w; tile < 42; tile += 4) {
            int rt = tile / 7, ct = tile % 7;
            int r  = rt * 16 + l15;
            int tv = ct * 16 + l15;
            f32x4 d = zf;
            #pragma unroll
            for (int ss = 0; ss < 2; ++ss) {
                int kb = ss * 4 + q;
                short8 af = *(const short8*)&ws[r * 64 + (((kb + r) & 7) << 3)];
                short8 bf = *(const short8*)&xT[tv * 64 + (((kb + tv) & 7) << 3)];
                d = __builtin_amdgcn_mfma_f32_16x16x32_bf16(af, bf, d, 0, 0, 0);
            }
            if (tv < 100) {
                int tl = tv / 25, v = tv % 25;
                int r0 = rt * 16 + q * 4;
                float b0 = bias[r0], b1 = bias[r0 + 1];
                float b2 = bias[r0 + 2], b3 = bias[r0 + 3];
                int kb = tl * 2 + (q >> 1);
                uint32* dst = (uint32*)&abT[(rt * 32 + v) * 64 +
                                            (((kb + v) & 7) << 3) + ((q & 1) << 2)];
                dst[0] = packbf2(d[0] + b0, d[1] + b1);
                dst[1] = packbf2(d[2] + b2, d[3] + b3);
            }
        }
        __syncthreads();
        // ---- phase B: wave w owns local t = w; M_i += a_i^T b_i
        {
            int kb = w * 2 + hi;
            #pragma unroll
            for (int i = 0; i < 3; ++i) {
                short8 af = *(const short8*)&abT[(i * 32 + v32) * 64 +
                                                 (((kb + v32) & 7) << 3)];
                short8 bf = *(const short8*)&abT[((3 + i) * 32 + v32) * 64 +
                                                 (((kb + v32) & 7) << 3)];
                acc[i] = __builtin_amdgcn_mfma_f32_32x32x16_bf16(af, bf, acc[i], 0, 0, 0);
            }
        }
    }

    // ---- cross-wave reduction in LDS (reuse xT region), then atomics
    float* Ms = (float*)xT;   // [3][32][33] f32 = 12672 B <= 14336 B
    __syncthreads();
    for (int idx = tid; idx < 3 * 32 * 33; idx += 256) Ms[idx] = 0.f;
    __syncthreads();
    for (int wv = 0; wv < 4; ++wv) {
        if (w == wv) {
            #pragma unroll
            for (int i = 0; i < 3; ++i)
                #pragma unroll
                for (int r = 0; r < 16; ++r) {
                    int row = (r & 3) + 8 * (r >> 2) + 4 * hi;   // m74/m101 C-layout
                    Ms[i * 1056 + row * 33 + v32] += acc[i][r];
                }
        }
        __syncthreads();
    }
    const float inv = 1.0f / 4800.0f;
    for (int idx = tid; idx < 1875; idx += 256) {
        int i = idx / 625, rem = idx % 625;
        int v1 = rem / 25, v2 = rem % 25;
        atomicAdd(Mb + ((i * NB + n) * 25 + v1) * 25 + v2,
                  Ms[i * 1056 + v1 * 33 + v2] * inv);
    }
}

// ---------------------------------------------------------------- kernel 2
// softmax over v1 per (i,n,v2) + A_tot -> atT bf16 [i][n][v2][v1 pad32]
// plus g_w -> gw_bf bf16 [o][k=i*64+c] (A-operand layout for k3)
__global__ __launch_bounds__(256) void k2_softmax_prep(
    const float* __restrict__ Mb, const float* __restrict__ A,
    const float* __restrict__ GA, const float* __restrict__ g_w,
    uint32* __restrict__ atT, uint32* __restrict__ gwb)
{
    int idx = blockIdx.x * 256 + threadIdx.x;
    if (idx < 4800) {
        int v2 = idx % 25, n = (idx / 25) % 64, i = idx / 1600;
        const float* mcol = Mb + ((i * 64 + n) * 25) * 25 + v2;
        float e[25], mx = -1e30f;
        #pragma unroll
        for (int v1 = 0; v1 < 25; ++v1) { e[v1] = mcol[v1 * 25]; mx = fmaxf(mx, e[v1]); }
        float s = 0.f;
        #pragma unroll
        for (int v1 = 0; v1 < 25; ++v1) { e[v1] = __expf(e[v1] - mx); s += e[v1]; }
        float invs = 1.0f / s;
        const float* acol = A + i * 625 + v2;
        const float* gcol = GA + i * 625 + v2;
        float w[25];
        #pragma unroll
        for (int v1 = 0; v1 < 25; ++v1)
            w[v1] = e[v1] * invs + acol[v1 * 25] + gcol[v1 * 25];
        uint32* row = atT + ((i * 64 + n) * 32 + v2) * 16;
        #pragma unroll
        for (int p = 0; p < 12; ++p) row[p] = packbf2(w[2 * p], w[2 * p + 1]);
        row[12] = (uint32)f2bf(w[24]);
        row[13] = 0u; row[14] = 0u; row[15] = 0u;
    } else if (idx < 4800 + 6144) {
        int j = idx - 4800;
        int o = j / 96, kp = j % 96;
        int k0 = 2 * kp;
        int i = k0 >> 6, c = k0 & 63;
        float lo = g_w[(i * 64 + o) * 64 + c];
        float hi = g_w[(i * 64 + o) * 64 + c + 1];
        gwb[o * 96 + kp] = packbf2(lo, hi);
    }
}

// ---------------------------------------------------------------- kernel 3
// MFMA. grid 3840 = 64 n * 60 chunks of 5 t; 256 thr = 4 waves (wave=o/c tile)
__global__ __launch_bounds__(256) void k3_out(
    const float* __restrict__ x, const uint32* __restrict__ atT,
    const ushort16* __restrict__ gwb, const float* __restrict__ g_b,
    const float* __restrict__ bn_g, const float* __restrict__ bn_b,
    const float* __restrict__ bn_m, const float* __restrict__ bn_v,
    float* __restrict__ out)
{
    __shared__ ushort16 xs[64 * 168];   // [c][t*32 + v1]  (stride 168: 2-way banks)
    __shared__ uint32  xa[128 * 36];    // [col=(t,v2) pad128][c: 72 bf16 as 36 u32]
    __shared__ uint32  ats[3 * 32 * 20];// [i][v2][v1: 40 bf16 as 20 u32]
    __shared__ float   bsc[64], bsh[64];

    const int tid = threadIdx.x;
    const int n  = blockIdx.x / 60;
    const int t0 = (blockIdx.x % 60) * 5;

    // stage x tile -> bf16 [c][t][v1]
    for (int idx = tid; idx < 8000; idx += 256) {
        int c = idx / 125, tv = idx % 125;
        int t = tv / 25, v = tv % 25;
        float g = x[((n * 64 + c) * 300 + t0 + t) * 25 + v];
        xs[c * 168 + t * 32 + v] = f2bf(g);
    }
    for (int idx = tid; idx < 64 * 35; idx += 256) {   // zero v1 in [25,32)
        int c = idx / 35, r = idx % 35;
        xs[c * 168 + (r / 7) * 32 + 25 + (r % 7)] = (ushort16)0;
    }
    // stage attn^T rows for this n
    for (int idx = tid; idx < 1536; idx += 256) {
        int row = idx >> 4, d = idx & 15;   // row = i*32+v2
        ats[row * 20 + d] = atT[((row >> 5) * 64 + n) * 512 + (row & 31) * 16 + d];
    }
    // BN scale/shift prefold (h = acc*sc + sh + x)
    for (int idx = tid; idx < 64; idx += 256) {
        float sc = bn_g[idx] * rsqrtf(bn_v[idx] + 1e-5f);
        bsc[idx] = sc;
        bsh[idx] = (g_b[idx] + g_b[64 + idx] + g_b[128 + idx] - bn_m[idx]) * sc + bn_b[idx];
    }
    // zero xa pad rows (cols 125..127)
    for (int idx = tid; idx < 3 * 36; idx += 256)
        xa[(125 + idx / 36) * 36 + idx % 36] = 0u;

    const int w    = tid >> 6;      // wave id = o-tile (main) = c-tile (xa)
    const int lane = tid & 63;
    const int l15  = lane & 15;
    const int q    = lane >> 4;

    // preload A-frags of gw (all 6 K-steps: k = i*64 + s*32)
    short8 gf[6];
    #pragma unroll
    for (int s = 0; s < 6; ++s)
        gf[s] = *(const short8*)(gwb + ((w * 16 + l15) * 192 + s * 32 + q * 8));

    f32x4 acc[8];
    #pragma unroll
    for (int ct = 0; ct < 8; ++ct) acc[ct] = (f32x4){0.f, 0.f, 0.f, 0.f};
    const f32x4 zf = (f32x4){0.f, 0.f, 0.f, 0.f};

    __syncthreads();

    for (int i = 0; i < 3; ++i) {
        if (i) __syncthreads();   // previous xa fully consumed
        // ---- xa-phase: this wave produces c-rows [w*16, w*16+16)
        #pragma unroll
        for (int t = 0; t < 5; ++t) {
            short8 ax = *(const short8*)(xs + (w * 16 + l15) * 168 + t * 32 + q * 8);
            #pragma unroll
            for (int vt = 0; vt < 2; ++vt) {
                short8 bt = *(const short8*)((const ushort16*)ats +
                                             (i * 32 + vt * 16 + l15) * 40 + q * 8);
                f32x4 d = __builtin_amdgcn_mfma_f32_16x16x32_bf16(ax, bt, zf, 0, 0, 0);
                int v2 = vt * 16 + l15;
                if (v2 < 25) {
                    int col = t * 25 + v2;
                    int c0  = w * 16 + q * 4;
                    xa[col * 36 + (c0 >> 1)]     = packbf2(d[0], d[1]);
                    xa[col * 36 + (c0 >> 1) + 1] = packbf2(d[2], d[3]);
                }
            }
        }
        __syncthreads();
        // ---- main GEMM: acc[o,col] += gw_i[o,c] * xa[c,col]
        #pragma unroll
        for (int ct = 0; ct < 8; ++ct) {
            #pragma unroll
            for (int s = 0; s < 2; ++s) {
                short8 bfrag = *(const short8*)((const ushort16*)xa +
                                                (ct * 16 + l15) * 72 + s * 32 + q * 8);
                acc[ct] = __builtin_amdgcn_mfma_f32_16x16x32_bf16(
                    gf[i * 2 + s], bfrag, acc[ct], 0, 0, 0);
            }
        }
    }

    // ---- epilogue: BN + residual (bf16 xs) + relu, direct coalesced store
    const int o0 = w * 16 + q * 4;
    #pragma unroll
    for (int ct = 0; ct < 8; ++ct) {
        int col = ct * 16 + l15;
        if (col < 125) {
            int tl = col / 25;
            int v  = col - tl * 25;
            float* ob = out + (n * 64 + o0) * 7500 + t0 * 25 + col;
            #pragma unroll
            for (int r = 0; r < 4; ++r) {
                int o = o0 + r;
                float xv = bf2f(xs[o * 168 + tl * 32 + v]);
                float h = acc[ct][r] * bsc[o] + bsh[o] + xv;
                ob[r * 7500] = fmaxf(h, 0.f);
            }
        }
    }
}

// ---------------------------------------------------------------- launch
extern "C" void kernel_launch(void* const* d_in, const int* in_sizes, int n_in,
                              void* d_out, int out_size, void* d_ws, size_t ws_size,
                              hipStream_t stream) {
    const float* x    = (const float*)d_in[0];
    const float* A    = (const float*)d_in[1];
    const float* GA   = (const float*)d_in[2];
    const float* g_w  = (const float*)d_in[3];
    const float* g_b  = (const float*)d_in[4];
    const float* a_w  = (const float*)d_in[5];
    const float* a_b  = (const float*)d_in[6];
    const float* b_w  = (const float*)d_in[7];
    const float* b_b  = (const float*)d_in[8];
    const float* bn_g = (const float*)d_in[9];
    const float* bn_b = (const float*)d_in[10];
    const float* bn_m = (const float*)d_in[11];
    const float* bn_v = (const float*)d_in[12];
    float* out = (float*)d_out;

    // ws: Mb f32[120000] (480000 B) | atT bf16 [3][64][32][32] (393216 B)
    //     | gw_bf bf16 [64][192] (24576 B)
    float*  Mb  = (float*)d_ws;
    uint32* atT = (uint32*)((char*)d_ws + 480000);
    uint32* gwb = (uint32*)((char*)d_ws + 480000 + 393216);

    hipMemsetAsync(d_ws, 0, 480000, stream);  // zero M accumulators
    k1_attn_logits_mfma<<<dim3(1600), dim3(256), 0, stream>>>(x, a_w, a_b, b_w, b_b, Mb);
    k2_softmax_prep<<<dim3(43), dim3(256), 0, stream>>>(Mb, A, GA, g_w, atT, gwb);
    k3_out<<<dim3(3840), dim3(256), 0, stream>>>(x, atT, (const ushort16*)gwb,
                                                 g_b, bn_g, bn_b, bn_m, bn_v, out);
}